// Round 17
// baseline (42.803 us; speedup 1.0000x reference)
//
#include <hip/hip_runtime.h>

#define NB 32
#define NN 2048
#define NC 16
#define ND 128
#define NH 128
#define TM 64
#define NBLK (NB * (NN / TM))   // 1024 blocks of 256 threads

typedef __bf16 bf16x8 __attribute__((ext_vector_type(8)));
typedef float f32x4 __attribute__((ext_vector_type(4)));
typedef float f32x2 __attribute__((ext_vector_type(2)));

__device__ __forceinline__ unsigned short f2bf(float f){
  unsigned u = __float_as_uint(f);
  u = (u + 0x7fffu + ((u >> 16) & 1u)) >> 16;   // RNE
  return (unsigned short)u;
}
__device__ __forceinline__ unsigned enc_f32(float x){
  unsigned u = __float_as_uint(x);
  return (u & 0x80000000u) ? ~u : (u | 0x80000000u);
}
__device__ __forceinline__ float dec_f32(unsigned u){
  return __uint_as_float((u & 0x80000000u) ? (u & 0x7fffffffu) : ~u);
}
// 4 f32 -> 4 fp8 (HW encode; matches HW decode)
__device__ __forceinline__ unsigned pack4f8(float a, float b, float c, float d){
  int r = __builtin_amdgcn_cvt_pk_fp8_f32(a, b, 0, false);
  r = __builtin_amdgcn_cvt_pk_fp8_f32(c, d, r, true);
  return (unsigned)r;
}

// swizzled LDS tile helpers (XOR bank swizzle: byte ^= (row&7)<<4)
__device__ __forceinline__ void stq(unsigned char* base, int stride, int row, int koff, uint4 u){
  *(uint4*)(base + row * stride + (koff ^ ((row & 7) << 4))) = u;
}
__device__ __forceinline__ void st8(unsigned char* base, int stride, int row, int koff, const float* f){
  uint4 u;
  u.x = (unsigned)f2bf(f[0]) | ((unsigned)f2bf(f[1]) << 16);
  u.y = (unsigned)f2bf(f[2]) | ((unsigned)f2bf(f[3]) << 16);
  u.z = (unsigned)f2bf(f[4]) | ((unsigned)f2bf(f[5]) << 16);
  u.w = (unsigned)f2bf(f[6]) | ((unsigned)f2bf(f[7]) << 16);
  stq(base, stride, row, koff, u);
}
// pack 4 f32x2 pairs (8 floats) -> 16B bf16 store
__device__ __forceinline__ void st8p(unsigned char* base, int stride, int row, int koff, const f32x2* p){
  uint4 u;
  u.x = (unsigned)f2bf(p[0][0]) | ((unsigned)f2bf(p[0][1]) << 16);
  u.y = (unsigned)f2bf(p[1][0]) | ((unsigned)f2bf(p[1][1]) << 16);
  u.z = (unsigned)f2bf(p[2][0]) | ((unsigned)f2bf(p[2][1]) << 16);
  u.w = (unsigned)f2bf(p[3][0]) | ((unsigned)f2bf(p[3][1]) << 16);
  stq(base, stride, row, koff, u);
}
__device__ __forceinline__ uint4 ldq(const unsigned char* base, int stride, int row, int koff){
  return *(const uint4*)(base + row * stride + (koff ^ ((row & 7) << 4)));
}

// ws layout
#define OFF_POOLED 0
#define OFF_W1     16384
#define OFF_W2     114688
#define OFF_EMB    147456
#define WS_NEED_F8 (OFF_EMB + (size_t)NB*NN*ND)   // fp8: 1 B/elem

// ---- unified prep ----
__global__ __launch_bounds__(256) void tbcnn_prep(
    const float* __restrict__ nodeEmb, const float* __restrict__ W1,
    const float* __restrict__ W2, unsigned* __restrict__ pooled,
    uint4* __restrict__ w1frag, uint4* __restrict__ w2frag,
    unsigned char* __restrict__ embF8, int doEmb)
{
  const int blk = blockIdx.x;
  const int t = threadIdx.x;
  if (blk < 2048){
    if (!doEmb) return;
    const int chk = ((blk & 7) << 8) | (blk >> 3);
    const int tid = chk * 256 + t;                // 0..524287
    const float4* src = (const float4*)nodeEmb;
    float4 v0 = src[tid * 4 + 0];
    float4 v1 = src[tid * 4 + 1];
    float4 v2 = src[tid * 4 + 2];
    float4 v3 = src[tid * 4 + 3];
    uint4 o;
    o.x = pack4f8(v0.x, v0.y, v0.z, v0.w);
    o.y = pack4f8(v1.x, v1.y, v1.z, v1.w);
    o.z = pack4f8(v2.x, v2.y, v2.z, v2.w);
    o.w = pack4f8(v3.x, v3.y, v3.z, v3.w);
    ((uint4*)embF8)[tid] = o;
  } else if (blk < 2072){
    const int tt = (blk - 2048) * 256 + t;        // 0..6143
    if (tt < NB * NH) pooled[tt] = 0u;            // enc-min (any real value wins)
    const int lane = tt & 63;
    const int rest = tt >> 6;                     // 0..95
    const int ks = rest % 12;
    const int cf = rest / 12;
    const int col = (cf >> 1) * 32 + (cf & 1) * 16 + (lane & 15);
    const int k0 = ks * 32 + (lane >> 4) * 8;
    unsigned ps[4];
    #pragma unroll
    for (int p = 0; p < 4; ++p){
      unsigned lo = f2bf(W1[(size_t)(k0 + 2*p) * NH + col]);
      unsigned hi = f2bf(W1[(size_t)(k0 + 2*p + 1) * NH + col]);
      ps[p] = lo | (hi << 16);
    }
    w1frag[tt] = make_uint4(ps[0], ps[1], ps[2], ps[3]);
  } else {
    const int tt = (blk - 2072) * 256 + t;        // 0..2047
    const int lane = tt & 63;
    const int rest = tt >> 6;
    const int ks = rest & 3;
    const int cf = rest >> 2;
    const int col = (cf >> 1) * 32 + (cf & 1) * 16 + (lane & 15);
    const int k0 = ks * 32 + (lane >> 4) * 8;
    unsigned ps[4];
    #pragma unroll
    for (int p = 0; p < 4; ++p){
      unsigned lo = f2bf(W2[(size_t)(k0 + 2*p) * NH + col]);
      unsigned hi = f2bf(W2[(size_t)(k0 + 2*p + 1) * NH + col]);
      ps[p] = lo | (hi << 16);
    }
    w2frag[tt] = make_uint4(ps[0], ps[1], ps[2], ps[3]);
  }
}

// decode one dword (4 fp8) and accumulate into pairs p, p+1 with packed FMA
#define PROCF8(u, p) { \
  f32x2 lo_ = __builtin_amdgcn_cvt_pk_f32_fp8((int)(u), false); \
  f32x2 hi_ = __builtin_amdgcn_cvt_pk_f32_fp8((int)(u), true); \
  aR2[(p)]   += w_r * lo_; aL2[(p)]   += w_l * lo_; \
  aR2[(p)+1] += w_r * hi_; aL2[(p)+1] += w_l * hi_; }

// issue 4 children's 16B fp8 loads (1 line per row)
#define ISSUE4(vv, D) { \
  D[0] = *(const uint4*)(embF8 + (rowbase + (unsigned)(vv).x) * ND + d0); \
  D[1] = *(const uint4*)(embF8 + (rowbase + (unsigned)(vv).y) * ND + d0); \
  D[2] = *(const uint4*)(embF8 + (rowbase + (unsigned)(vv).z) * ND + d0); \
  D[3] = *(const uint4*)(embF8 + (rowbase + (unsigned)(vv).w) * ND + d0); }

#define CW(c, idx) \
  const float mk  = ((idx) > 0) ? 1.0f : 0.0f; \
  const float wrc = one_sib ? (0.5f * mk) : (mk * (float)(c) * rdiv); \
  const float wlc = (1.0f - wrc) * mk; \
  const f32x2 w_r = (f32x2){wrc, wrc}; \
  const f32x2 w_l = (f32x2){wlc, wlc};

// process 4 children of group g from staged buffer U
#define PROC4(g, vv, U) { \
  { CW(4*(g)+0, (vv).x) PROCF8(U[0].x,0) PROCF8(U[0].y,2) PROCF8(U[0].z,4) PROCF8(U[0].w,6) } \
  { CW(4*(g)+1, (vv).y) PROCF8(U[1].x,0) PROCF8(U[1].y,2) PROCF8(U[1].z,4) PROCF8(U[1].w,6) } \
  { CW(4*(g)+2, (vv).z) PROCF8(U[2].x,0) PROCF8(U[2].y,2) PROCF8(U[2].z,4) PROCF8(U[2].w,6) } \
  { CW(4*(g)+3, (vv).w) PROCF8(U[3].x,0) PROCF8(U[3].y,2) PROCF8(U[3].z,4) PROCF8(U[3].w,6) } }

// self-row convert + store to wf (8 f32x2 from one uint4 of 16 fp8)
#define SELF_STORE(SQ, ROW) { \
  f32x2 sv[8]; \
  sv[0] = __builtin_amdgcn_cvt_pk_f32_fp8((int)(SQ).x, false); \
  sv[1] = __builtin_amdgcn_cvt_pk_f32_fp8((int)(SQ).x, true); \
  sv[2] = __builtin_amdgcn_cvt_pk_f32_fp8((int)(SQ).y, false); \
  sv[3] = __builtin_amdgcn_cvt_pk_f32_fp8((int)(SQ).y, true); \
  sv[4] = __builtin_amdgcn_cvt_pk_f32_fp8((int)(SQ).z, false); \
  sv[5] = __builtin_amdgcn_cvt_pk_f32_fp8((int)(SQ).z, true); \
  sv[6] = __builtin_amdgcn_cvt_pk_f32_fp8((int)(SQ).w, false); \
  sv[7] = __builtin_amdgcn_cvt_pk_f32_fp8((int)(SQ).w, true); \
  st8p(wf_raw, 768, (ROW), 2 * d0,       sv); \
  st8p(wf_raw, 768, (ROW), 2 * (d0 + 8), sv + 4); }

// one K-step of the rf01 MFMA (rows 0..31, both col-frags)
#define MFMA01(KS) { \
  bf16x8 B0_ = __builtin_bit_cast(bf16x8, w1frag[((w * 2 + 0) * 12 + (KS)) * 64 + lane]); \
  bf16x8 B1_ = __builtin_bit_cast(bf16x8, w1frag[((w * 2 + 1) * 12 + (KS)) * 64 + lane]); \
  const int koff_ = (KS) * 64 + ((lane >> 4) << 4); \
  bf16x8 a0_ = __builtin_bit_cast(bf16x8, ldq(wf_raw, 768, (lane & 15),      koff_)); \
  bf16x8 a1_ = __builtin_bit_cast(bf16x8, ldq(wf_raw, 768, 16 + (lane & 15), koff_)); \
  acc[0][0] = __builtin_amdgcn_mfma_f32_16x16x32_bf16(a0_, B0_, acc[0][0], 0, 0, 0); \
  acc[0][1] = __builtin_amdgcn_mfma_f32_16x16x32_bf16(a0_, B1_, acc[0][1], 0, 0, 0); \
  acc[1][0] = __builtin_amdgcn_mfma_f32_16x16x32_bf16(a1_, B0_, acc[1][0], 0, 0, 0); \
  acc[1][1] = __builtin_amdgcn_mfma_f32_16x16x32_bf16(a1_, B1_, acc[1][1], 0, 0, 0); }

// ---- main: TM=64; pass1 gather -> {pass2 gather || MFMA rf01} -> MFMA rf23 ----
// R17: pass1 fills wf rows 0..31 completely, so the rf01 K-loop overlaps with
// pass2's gather (rows 32..63; no LDS conflict, single sync after pass1).
// Kept: (256,2) only (R2/R4 spill); no fence/ticket (R5/R9); 8-thr/node
// (R11/R12 worse); fp8 rows = 1 line (R13); TM=64 (R14).
template<bool F8>
__global__ __launch_bounds__(256, 2) void tbcnn_main(
    const int* __restrict__ children, const float* __restrict__ nodeEmb,
    const unsigned char* __restrict__ embF8, const uint4* __restrict__ w1frag,
    unsigned* __restrict__ pooled)
{
  __shared__ __align__(16) unsigned char wf_raw[TM * 768];   // 48 KB
  // XCD-aware swizzle: 1024 blocks = 8 XCDs x 128; each XCD owns 4 batches
  const int j0 = ((blockIdx.x & 7) << 7) | (blockIdx.x >> 3);
  const int b = j0 >> 5;
  const int n0 = (j0 & 31) * TM;
  const int t = threadIdx.x;
  const int lane = t & 63;
  const int w = t >> 6;
  const size_t rowbase = (size_t)b * NN;
  const int q = t & 7;
  const int d0 = q * 16;              // dim == byte offset in fp8 row

  f32x4 acc[4][2];
  #pragma unroll
  for (int rf = 0; rf < 4; ++rf){
    acc[rf][0] = (f32x4){0.f, 0.f, 0.f, 0.f};
    acc[rf][1] = (f32x4){0.f, 0.f, 0.f, 0.f};
  }

  if (F8){
    // ---- pass 1: nodes 0..31 (R13 2-group staged pipeline) ----
    {
      const int nloc = t >> 3;
      const int gn = n0 + nloc;
      const int4* chp4 = (const int4*)(children + (rowbase + gn) * NC);
      const int4 vA = chp4[0], vB = chp4[1], vC = chp4[2], vD = chp4[3];
      int ns = (vA.x > 0) + (vA.y > 0) + (vA.z > 0) + (vA.w > 0)
             + (vB.x > 0) + (vB.y > 0) + (vB.z > 0) + (vB.w > 0)
             + (vC.x > 0) + (vC.y > 0) + (vC.z > 0) + (vC.w > 0)
             + (vD.x > 0) + (vD.y > 0) + (vD.z > 0) + (vD.w > 0);
      const float rdiv = 1.0f / (float)(((ns - 1) > 1) ? (ns - 1) : 1);
      const bool one_sib = (ns == 1);

      f32x2 aR2[8], aL2[8];
      #pragma unroll
      for (int i = 0; i < 8; ++i){ aR2[i] = (f32x2){0.f,0.f}; aL2[i] = (f32x2){0.f,0.f}; }
      uint4 g0[4], g1[4];
      const uint4 sq = *(const uint4*)(embF8 + (rowbase + gn) * ND + d0);
      ISSUE4(vA, g0)
      ISSUE4(vB, g1)
      __builtin_amdgcn_sched_barrier(0);
      SELF_STORE(sq, nloc)
      PROC4(0, vA, g0)
      ISSUE4(vC, g0)
      __builtin_amdgcn_sched_barrier(0);
      PROC4(1, vB, g1)
      ISSUE4(vD, g1)
      __builtin_amdgcn_sched_barrier(0);
      PROC4(2, vC, g0)
      __builtin_amdgcn_sched_barrier(0);
      PROC4(3, vD, g1)
      st8p(wf_raw, 768, nloc, 2 * (ND + d0),         aR2);
      st8p(wf_raw, 768, nloc, 2 * (ND + d0 + 8),     aR2 + 4);
      st8p(wf_raw, 768, nloc, 2 * (2 * ND + d0),     aL2);
      st8p(wf_raw, 768, nloc, 2 * (2 * ND + d0 + 8), aL2 + 4);
    }
    __syncthreads();   // rows 0..31 complete

    // ---- pass 2 (rows 32..63) overlapped with MFMA rf01 (rows 0..31) ----
    {
      const int nloc = 32 + (t >> 3);
      const int gn = n0 + nloc;
      const int4* chp4 = (const int4*)(children + (rowbase + gn) * NC);
      const int4 vA = chp4[0], vB = chp4[1], vC = chp4[2], vD = chp4[3];
      int ns = (vA.x > 0) + (vA.y > 0) + (vA.z > 0) + (vA.w > 0)
             + (vB.x > 0) + (vB.y > 0) + (vB.z > 0) + (vB.w > 0)
             + (vC.x > 0) + (vC.y > 0) + (vC.z > 0) + (vC.w > 0)
             + (vD.x > 0) + (vD.y > 0) + (vD.z > 0) + (vD.w > 0);
      const float rdiv = 1.0f / (float)(((ns - 1) > 1) ? (ns - 1) : 1);
      const bool one_sib = (ns == 1);

      f32x2 aR2[8], aL2[8];
      #pragma unroll
      for (int i = 0; i < 8; ++i){ aR2[i] = (f32x2){0.f,0.f}; aL2[i] = (f32x2){0.f,0.f}; }
      uint4 g0[4], g1[4];
      const uint4 sq = *(const uint4*)(embF8 + (rowbase + gn) * ND + d0);
      ISSUE4(vA, g0)
      ISSUE4(vB, g1)
      __builtin_amdgcn_sched_barrier(0);
      // MFMA rf01 first half hides A/B latency
      MFMA01(0) MFMA01(1) MFMA01(2) MFMA01(3) MFMA01(4) MFMA01(5)
      __builtin_amdgcn_sched_barrier(0);
      SELF_STORE(sq, nloc)
      PROC4(0, vA, g0)
      ISSUE4(vC, g0)
      __builtin_amdgcn_sched_barrier(0);
      // MFMA rf01 second half hides C latency
      MFMA01(6) MFMA01(7) MFMA01(8) MFMA01(9) MFMA01(10) MFMA01(11)
      __builtin_amdgcn_sched_barrier(0);
      PROC4(1, vB, g1)
      ISSUE4(vD, g1)
      __builtin_amdgcn_sched_barrier(0);
      PROC4(2, vC, g0)
      __builtin_amdgcn_sched_barrier(0);
      PROC4(3, vD, g1)
      st8p(wf_raw, 768, nloc, 2 * (ND + d0),         aR2);
      st8p(wf_raw, 768, nloc, 2 * (ND + d0 + 8),     aR2 + 4);
      st8p(wf_raw, 768, nloc, 2 * (2 * ND + d0),     aL2);
      st8p(wf_raw, 768, nloc, 2 * (2 * ND + d0 + 8), aL2 + 4);
    }
    __syncthreads();   // rows 32..63 complete

    // ---- MFMA rf23 (rows 32..63), K=384 ----
    #pragma unroll 4
    for (int ks = 0; ks < 12; ++ks){
      bf16x8 B0 = __builtin_bit_cast(bf16x8, w1frag[((w * 2 + 0) * 12 + ks) * 64 + lane]);
      bf16x8 B1 = __builtin_bit_cast(bf16x8, w1frag[((w * 2 + 1) * 12 + ks) * 64 + lane]);
      const int koff = ks * 64 + ((lane >> 4) << 4);
      #pragma unroll
      for (int rf = 2; rf < 4; ++rf){
        const int row = rf * 16 + (lane & 15);
        bf16x8 a = __builtin_bit_cast(bf16x8, ldq(wf_raw, 768, row, koff));
        acc[rf][0] = __builtin_amdgcn_mfma_f32_16x16x32_bf16(a, B0, acc[rf][0], 0, 0, 0);
        acc[rf][1] = __builtin_amdgcn_mfma_f32_16x16x32_bf16(a, B1, acc[rf][1], 0, 0, 0);
      }
    }
  } else {
    // f32 fallback (ws too small): R14 sequential structure
    #pragma unroll
    for (int pass = 0; pass < 2; ++pass){
      const int nloc = pass * 32 + (t >> 3);
      const int gn = n0 + nloc;
      const int4* chp4 = (const int4*)(children + (rowbase + gn) * NC);
      const int4 vA = chp4[0], vB = chp4[1], vC = chp4[2], vD = chp4[3];
      int ns = (vA.x > 0) + (vA.y > 0) + (vA.z > 0) + (vA.w > 0)
             + (vB.x > 0) + (vB.y > 0) + (vB.z > 0) + (vB.w > 0)
             + (vC.x > 0) + (vC.y > 0) + (vC.z > 0) + (vC.w > 0)
             + (vD.x > 0) + (vD.y > 0) + (vD.z > 0) + (vD.w > 0);
      const float rdiv = 1.0f / (float)(((ns - 1) > 1) ? (ns - 1) : 1);
      const bool one_sib = (ns == 1);
      const float* sp = nodeEmb + (rowbase + gn) * ND + d0;
      float sv[16];
      #pragma unroll
      for (int j = 0; j < 4; ++j){
        float4 s = *(const float4*)(sp + j * 4);
        sv[j*4+0]=s.x; sv[j*4+1]=s.y; sv[j*4+2]=s.z; sv[j*4+3]=s.w;
      }
      st8(wf_raw, 768, nloc, 2 * d0, sv);
      st8(wf_raw, 768, nloc, 2 * (d0 + 8), sv + 8);
      float aR[16], aL[16];
      #pragma unroll
      for (int i = 0; i < 16; ++i){ aR[i] = 0.0f; aL[i] = 0.0f; }
      const int4 vs[4] = {vA, vB, vC, vD};
      #pragma unroll
      for (int c4 = 0; c4 < 4; ++c4){
        int cidx[4] = {vs[c4].x, vs[c4].y, vs[c4].z, vs[c4].w};
        #pragma unroll
        for (int jj = 0; jj < 4; ++jj){
          const int c = c4 * 4 + jj;
          const int idx = cidx[jj];
          const float mk  = (idx > 0) ? 1.0f : 0.0f;
          const float wrc = one_sib ? (0.5f * mk) : (mk * (float)c * rdiv);
          const float wlc = (1.0f - wrc) * mk;
          const float* cp = nodeEmb + (rowbase + idx) * ND + d0;
          #pragma unroll
          for (int j = 0; j < 4; ++j){
            float4 u = *(const float4*)(cp + j * 4);
            aR[j*4+0] += wrc * u.x; aL[j*4+0] += wlc * u.x;
            aR[j*4+1] += wrc * u.y; aL[j*4+1] += wlc * u.y;
            aR[j*4+2] += wrc * u.z; aL[j*4+2] += wlc * u.z;
            aR[j*4+3] += wrc * u.w; aL[j*4+3] += wlc * u.w;
          }
        }
      }
      st8(wf_raw, 768, nloc, 2 * (ND + d0),         aR);
      st8(wf_raw, 768, nloc, 2 * (ND + d0 + 8),     aR + 8);
      st8(wf_raw, 768, nloc, 2 * (2 * ND + d0),     aL);
      st8(wf_raw, 768, nloc, 2 * (2 * ND + d0 + 8), aL + 8);
    }
    __syncthreads();
    #pragma unroll 4
    for (int ks = 0; ks < 12; ++ks){
      bf16x8 B0 = __builtin_bit_cast(bf16x8, w1frag[((w * 2 + 0) * 12 + ks) * 64 + lane]);
      bf16x8 B1 = __builtin_bit_cast(bf16x8, w1frag[((w * 2 + 1) * 12 + ks) * 64 + lane]);
      const int koff = ks * 64 + ((lane >> 4) << 4);
      #pragma unroll
      for (int rf = 0; rf < 4; ++rf){
        const int row = rf * 16 + (lane & 15);
        bf16x8 a = __builtin_bit_cast(bf16x8, ldq(wf_raw, 768, row, koff));
        acc[rf][0] = __builtin_amdgcn_mfma_f32_16x16x32_bf16(a, B0, acc[rf][0], 0, 0, 0);
        acc[rf][1] = __builtin_amdgcn_mfma_f32_16x16x32_bf16(a, B1, acc[rf][1], 0, 0, 0);
      }
    }
  }

  // ---- epilogue: row-max (tanh deferred) + atomic pool ----
  {
    float m0 = -3.0e38f, m1 = -3.0e38f;
    #pragma unroll
    for (int rf = 0; rf < 4; ++rf)
      #pragma unroll
      for (int i = 0; i < 4; ++i){
        m0 = fmaxf(m0, acc[rf][0][i]);
        m1 = fmaxf(m1, acc[rf][1][i]);
      }
    m0 = fmaxf(m0, __shfl_xor(m0, 16, 64));
    m0 = fmaxf(m0, __shfl_xor(m0, 32, 64));
    m1 = fmaxf(m1, __shfl_xor(m1, 16, 64));
    m1 = fmaxf(m1, __shfl_xor(m1, 32, 64));
    if (lane < 16){
      atomicMax(pooled + b * NH + w * 32 + lane,      enc_f32(m0));
      atomicMax(pooled + b * NH + w * 32 + 16 + lane, enc_f32(m1));
    }
  }
}

// ---- final: h=tanh(pooled+b1) -> MFMA h@W2 -> tanh -> cosine(v1,v2) ----
__global__ __launch_bounds__(256) void tbcnn_final(
    const unsigned* __restrict__ pooled, const float* __restrict__ b1,
    const uint4* __restrict__ w2frag, const float* __restrict__ b2,
    float* __restrict__ out)
{
  __shared__ __align__(16) unsigned char hls[NB * 256];   // 32 x 128 bf16, swizzled
  __shared__ float os[NB * NH];
  const int t = threadIdx.x;
  const int lane = t & 63;
  const int w = t >> 6;

  {
    const int row = t >> 3;          // batch
    const int q = t & 7;
    const int d0 = q * 16;
    const unsigned* pp = pooled + row * NH + d0;
    const float* bp = b1 + d0;
    float hv[16];
    #pragma unroll
    for (int j = 0; j < 16; ++j) hv[j] = tanhf(dec_f32(pp[j]) + bp[j]);
    st8(hls, 256, row, 2 * d0, hv);
    st8(hls, 256, row, 2 * (d0 + 8), hv + 8);
  }
  __syncthreads();
  {
    f32x4 acc[2][2];
    #pragma unroll
    for (int rf = 0; rf < 2; ++rf){
      acc[rf][0] = (f32x4){0.f,0.f,0.f,0.f};
      acc[rf][1] = (f32x4){0.f,0.f,0.f,0.f};
    }
    #pragma unroll
    for (int ks = 0; ks < 4; ++ks){
      bf16x8 B0 = __builtin_bit_cast(bf16x8, w2frag[((w * 2 + 0) * 4 + ks) * 64 + lane]);
      bf16x8 B1 = __builtin_bit_cast(bf16x8, w2frag[((w * 2 + 1) * 4 + ks) * 64 + lane]);
      const int koff = ks * 64 + ((lane >> 4) << 4);
      #pragma unroll
      for (int rf = 0; rf < 2; ++rf){
        bf16x8 a = __builtin_bit_cast(bf16x8, ldq(hls, 256, rf * 16 + (lane & 15), koff));
        acc[rf][0] = __builtin_amdgcn_mfma_f32_16x16x32_bf16(a, B0, acc[rf][0], 0, 0, 0);
        acc[rf][1] = __builtin_amdgcn_mfma_f32_16x16x32_bf16(a, B1, acc[rf][1], 0, 0, 0);
      }
    }
    #pragma unroll
    for (int rf = 0; rf < 2; ++rf)
      #pragma unroll
      for (int cf = 0; cf < 2; ++cf){
        const int col = w * 32 + cf * 16 + (lane & 15);
        const float bias = b2[col];
        #pragma unroll
        for (int i = 0; i < 4; ++i){
          const int r = rf * 16 + (lane >> 4) * 4 + i;
          os[r * NH + col] = tanhf(acc[rf][cf][i] + bias);
        }
      }
  }
  __syncthreads();
  if (t < 16){
    float s12 = 0.f, s11 = 0.f, s22 = 0.f;
    #pragma unroll 4
    for (int d = 0; d < NH; ++d){
      float a = os[t * NH + d];
      float c = os[(t + 16) * NH + d];
      s12 += a * c; s11 += a * a; s22 += c * c;
    }
    float n1 = fmaxf(sqrtf(s11), 1e-8f);
    float n2 = fmaxf(sqrtf(s22), 1e-8f);
    out[t] = s12 / (n1 * n2);
  }
}

extern "C" void kernel_launch(void* const* d_in, const int* in_sizes, int n_in,
                              void* d_out, int out_size, void* d_ws, size_t ws_size,
                              hipStream_t stream)
{
  const int*   children = (const int*)d_in[0];
  const float* nodeEmb  = (const float*)d_in[1];
  const float* W1       = (const float*)d_in[2];
  const float* b1       = (const float*)d_in[3];
  const float* W2       = (const float*)d_in[4];
  const float* b2       = (const float*)d_in[5];
  float* out = (float*)d_out;

  unsigned* pooled      = (unsigned*)((char*)d_ws + OFF_POOLED);
  uint4* w1frag         = (uint4*)((char*)d_ws + OFF_W1);
  uint4* w2frag         = (uint4*)((char*)d_ws + OFF_W2);
  unsigned char* embF8  = (unsigned char*)((char*)d_ws + OFF_EMB);

  const bool f8 = (ws_size >= WS_NEED_F8);

  tbcnn_prep<<<2080, 256, 0, stream>>>(nodeEmb, W1, W2, pooled, w1frag, w2frag, embF8, f8 ? 1 : 0);
  if (f8)
    tbcnn_main<true><<<NBLK, 256, 0, stream>>>(children, nodeEmb, embF8, w1frag, pooled);
  else
    tbcnn_main<false><<<NBLK, 256, 0, stream>>>(children, nodeEmb, embF8, w1frag, pooled);
  tbcnn_final<<<1, 256, 0, stream>>>(pooled, b1, w2frag, b2, out);
}

// Round 18
// 40.906 us; speedup vs baseline: 1.0464x; 1.0464x over previous
//
#include <hip/hip_runtime.h>

#define NB 32
#define NN 2048
#define NC 16
#define ND 128
#define NH 128
#define TM 64
#define NBLK (NB * (NN / TM))   // 1024 blocks of 256 threads

typedef __bf16 bf16x8 __attribute__((ext_vector_type(8)));
typedef float f32x4 __attribute__((ext_vector_type(4)));
typedef float f32x2 __attribute__((ext_vector_type(2)));

__device__ __forceinline__ unsigned short f2bf(float f){
  unsigned u = __float_as_uint(f);
  u = (u + 0x7fffu + ((u >> 16) & 1u)) >> 16;   // RNE
  return (unsigned short)u;
}
__device__ __forceinline__ unsigned enc_f32(float x){
  unsigned u = __float_as_uint(x);
  return (u & 0x80000000u) ? ~u : (u | 0x80000000u);
}
__device__ __forceinline__ float dec_f32(unsigned u){
  return __uint_as_float((u & 0x80000000u) ? (u & 0x7fffffffu) : ~u);
}
// 4 f32 -> 4 fp8 (HW encode; matches HW decode)
__device__ __forceinline__ unsigned pack4f8(float a, float b, float c, float d){
  int r = __builtin_amdgcn_cvt_pk_fp8_f32(a, b, 0, false);
  r = __builtin_amdgcn_cvt_pk_fp8_f32(c, d, r, true);
  return (unsigned)r;
}

// swizzled LDS tile helpers (XOR bank swizzle: byte ^= (row&7)<<4)
__device__ __forceinline__ void stq(unsigned char* base, int stride, int row, int koff, uint4 u){
  *(uint4*)(base + row * stride + (koff ^ ((row & 7) << 4))) = u;
}
__device__ __forceinline__ void st8(unsigned char* base, int stride, int row, int koff, const float* f){
  uint4 u;
  u.x = (unsigned)f2bf(f[0]) | ((unsigned)f2bf(f[1]) << 16);
  u.y = (unsigned)f2bf(f[2]) | ((unsigned)f2bf(f[3]) << 16);
  u.z = (unsigned)f2bf(f[4]) | ((unsigned)f2bf(f[5]) << 16);
  u.w = (unsigned)f2bf(f[6]) | ((unsigned)f2bf(f[7]) << 16);
  stq(base, stride, row, koff, u);
}
// pack 4 f32x2 pairs (8 floats) -> 16B bf16 store
__device__ __forceinline__ void st8p(unsigned char* base, int stride, int row, int koff, const f32x2* p){
  uint4 u;
  u.x = (unsigned)f2bf(p[0][0]) | ((unsigned)f2bf(p[0][1]) << 16);
  u.y = (unsigned)f2bf(p[1][0]) | ((unsigned)f2bf(p[1][1]) << 16);
  u.z = (unsigned)f2bf(p[2][0]) | ((unsigned)f2bf(p[2][1]) << 16);
  u.w = (unsigned)f2bf(p[3][0]) | ((unsigned)f2bf(p[3][1]) << 16);
  stq(base, stride, row, koff, u);
}
__device__ __forceinline__ uint4 ldq(const unsigned char* base, int stride, int row, int koff){
  return *(const uint4*)(base + row * stride + (koff ^ ((row & 7) << 4)));
}

// ws layout
#define OFF_POOLED 0
#define OFF_W1     16384
#define OFF_W2     114688
#define OFF_EMB    147456
#define WS_NEED_F8 (OFF_EMB + (size_t)NB*NN*ND)   // fp8: 1 B/elem

// ---- unified prep ----
// blocks [0,2048): nodeEmb f32 -> fp8 e4m3 (HW cvt), XCD-affine
// blocks [2048,2072): W1 frags [cf][ks][lane]x16B ; pooled init
// blocks [2072,2080): W2 frags [cf][ks][lane]x16B
__global__ __launch_bounds__(256) void tbcnn_prep(
    const float* __restrict__ nodeEmb, const float* __restrict__ W1,
    const float* __restrict__ W2, unsigned* __restrict__ pooled,
    uint4* __restrict__ w1frag, uint4* __restrict__ w2frag,
    unsigned char* __restrict__ embF8, int doEmb)
{
  const int blk = blockIdx.x;
  const int t = threadIdx.x;
  if (blk < 2048){
    if (!doEmb) return;
    const int chk = ((blk & 7) << 8) | (blk >> 3);
    const int tid = chk * 256 + t;                // 0..524287
    const float4* src = (const float4*)nodeEmb;
    float4 v0 = src[tid * 4 + 0];
    float4 v1 = src[tid * 4 + 1];
    float4 v2 = src[tid * 4 + 2];
    float4 v3 = src[tid * 4 + 3];
    uint4 o;
    o.x = pack4f8(v0.x, v0.y, v0.z, v0.w);
    o.y = pack4f8(v1.x, v1.y, v1.z, v1.w);
    o.z = pack4f8(v2.x, v2.y, v2.z, v2.w);
    o.w = pack4f8(v3.x, v3.y, v3.z, v3.w);
    ((uint4*)embF8)[tid] = o;
  } else if (blk < 2072){
    const int tt = (blk - 2048) * 256 + t;        // 0..6143
    if (tt < NB * NH) pooled[tt] = 0u;            // enc-min (any real value wins)
    const int lane = tt & 63;
    const int rest = tt >> 6;                     // 0..95
    const int ks = rest % 12;
    const int cf = rest / 12;
    const int col = (cf >> 1) * 32 + (cf & 1) * 16 + (lane & 15);
    const int k0 = ks * 32 + (lane >> 4) * 8;
    unsigned ps[4];
    #pragma unroll
    for (int p = 0; p < 4; ++p){
      unsigned lo = f2bf(W1[(size_t)(k0 + 2*p) * NH + col]);
      unsigned hi = f2bf(W1[(size_t)(k0 + 2*p + 1) * NH + col]);
      ps[p] = lo | (hi << 16);
    }
    w1frag[tt] = make_uint4(ps[0], ps[1], ps[2], ps[3]);
  } else {
    const int tt = (blk - 2072) * 256 + t;        // 0..2047
    const int lane = tt & 63;
    const int rest = tt >> 6;
    const int ks = rest & 3;
    const int cf = rest >> 2;
    const int col = (cf >> 1) * 32 + (cf & 1) * 16 + (lane & 15);
    const int k0 = ks * 32 + (lane >> 4) * 8;
    unsigned ps[4];
    #pragma unroll
    for (int p = 0; p < 4; ++p){
      unsigned lo = f2bf(W2[(size_t)(k0 + 2*p) * NH + col]);
      unsigned hi = f2bf(W2[(size_t)(k0 + 2*p + 1) * NH + col]);
      ps[p] = lo | (hi << 16);
    }
    w2frag[tt] = make_uint4(ps[0], ps[1], ps[2], ps[3]);
  }
}

// decode one dword (4 fp8) and accumulate into pairs p, p+1 with packed FMA
#define PROCF8(u, p) { \
  f32x2 lo_ = __builtin_amdgcn_cvt_pk_f32_fp8((int)(u), false); \
  f32x2 hi_ = __builtin_amdgcn_cvt_pk_f32_fp8((int)(u), true); \
  aR2[(p)]   += w_r * lo_; aL2[(p)]   += w_l * lo_; \
  aR2[(p)+1] += w_r * hi_; aL2[(p)+1] += w_l * hi_; }

// issue 4 children's 16B fp8 loads (1 line per row)
#define ISSUE4(vv, D) { \
  D[0] = *(const uint4*)(embF8 + (rowbase + (unsigned)(vv).x) * ND + d0); \
  D[1] = *(const uint4*)(embF8 + (rowbase + (unsigned)(vv).y) * ND + d0); \
  D[2] = *(const uint4*)(embF8 + (rowbase + (unsigned)(vv).z) * ND + d0); \
  D[3] = *(const uint4*)(embF8 + (rowbase + (unsigned)(vv).w) * ND + d0); }

#define CW(c, idx) \
  const float mk  = ((idx) > 0) ? 1.0f : 0.0f; \
  const float wrc = one_sib ? (0.5f * mk) : (mk * (float)(c) * rdiv); \
  const float wlc = (1.0f - wrc) * mk; \
  const f32x2 w_r = (f32x2){wrc, wrc}; \
  const f32x2 w_l = (f32x2){wlc, wlc};

// process 4 children of group g from staged buffer U
#define PROC4(g, vv, U) { \
  { CW(4*(g)+0, (vv).x) PROCF8(U[0].x,0) PROCF8(U[0].y,2) PROCF8(U[0].z,4) PROCF8(U[0].w,6) } \
  { CW(4*(g)+1, (vv).y) PROCF8(U[1].x,0) PROCF8(U[1].y,2) PROCF8(U[1].z,4) PROCF8(U[1].w,6) } \
  { CW(4*(g)+2, (vv).z) PROCF8(U[2].x,0) PROCF8(U[2].y,2) PROCF8(U[2].z,4) PROCF8(U[2].w,6) } \
  { CW(4*(g)+3, (vv).w) PROCF8(U[3].x,0) PROCF8(U[3].y,2) PROCF8(U[3].z,4) PROCF8(U[3].w,6) } }

// ---- main: TM=64 (2 gather passes) fp8 gather + wf (LDS) + MFMA + atomicMax ----
// Final configuration (best measured: 40.9us total). Lessons encoded:
// - (256,2) only: VGPR caps below ~64 spill 300MB scratch (R2/R4).
// - No __threadfence (R5: device fence demoted L2 gather set), no exit ticket
//   (R9: atomicAdd(done)+single-CU tail cost 7-10us).
// - 8-thr/node layout (R11/R12 wave-per-node was net worse).
// - fp8 rows = 1 cache line: the single biggest win (R13, -4.3us) — gather is
//   L1-miss line-service bound.
// - TM=64 halves W1 re-reads (R14, small gain). Deeper staging (R15), 512-thr
//   (R16), gather||MFMA overlap (R17) all null or negative: latency floor.
template<bool F8>
__global__ __launch_bounds__(256, 2) void tbcnn_main(
    const int* __restrict__ children, const float* __restrict__ nodeEmb,
    const unsigned char* __restrict__ embF8, const uint4* __restrict__ w1frag,
    unsigned* __restrict__ pooled)
{
  __shared__ __align__(16) unsigned char wf_raw[TM * 768];   // 48 KB
  // XCD-aware swizzle: 1024 blocks = 8 XCDs x 128; each XCD owns 4 batches
  const int j0 = ((blockIdx.x & 7) << 7) | (blockIdx.x >> 3);
  const int b = j0 >> 5;
  const int n0 = (j0 & 31) * TM;
  const int t = threadIdx.x;
  const int lane = t & 63;
  const int w = t >> 6;
  const size_t rowbase = (size_t)b * NN;

  // ---- gather: two passes of 32 nodes; 8 threads per node, 16 dims each ----
  #pragma unroll
  for (int pass = 0; pass < 2; ++pass){
    const int nloc = pass * 32 + (t >> 3);
    const int q = t & 7;
    const int d0 = q * 16;          // dim == byte offset in fp8 row
    const int gn = n0 + nloc;
    const int4* chp4 = (const int4*)(children + (rowbase + gn) * NC);

    const int4 vA = chp4[0], vB = chp4[1], vC = chp4[2], vD = chp4[3];
    int ns = (vA.x > 0) + (vA.y > 0) + (vA.z > 0) + (vA.w > 0)
           + (vB.x > 0) + (vB.y > 0) + (vB.z > 0) + (vB.w > 0)
           + (vC.x > 0) + (vC.y > 0) + (vC.z > 0) + (vC.w > 0)
           + (vD.x > 0) + (vD.y > 0) + (vD.z > 0) + (vD.w > 0);
    const float rdiv = 1.0f / (float)(((ns - 1) > 1) ? (ns - 1) : 1);
    const bool one_sib = (ns == 1);

    if (F8){
      f32x2 aR2[8], aL2[8];
      #pragma unroll
      for (int i = 0; i < 8; ++i){ aR2[i] = (f32x2){0.f,0.f}; aL2[i] = (f32x2){0.f,0.f}; }

      uint4 g0[4], g1[4];
      const uint4 sq = *(const uint4*)(embF8 + (rowbase + gn) * ND + d0);
      ISSUE4(vA, g0)
      ISSUE4(vB, g1)
      __builtin_amdgcn_sched_barrier(0);
      {
        f32x2 sv[8];
        sv[0] = __builtin_amdgcn_cvt_pk_f32_fp8((int)sq.x, false);
        sv[1] = __builtin_amdgcn_cvt_pk_f32_fp8((int)sq.x, true);
        sv[2] = __builtin_amdgcn_cvt_pk_f32_fp8((int)sq.y, false);
        sv[3] = __builtin_amdgcn_cvt_pk_f32_fp8((int)sq.y, true);
        sv[4] = __builtin_amdgcn_cvt_pk_f32_fp8((int)sq.z, false);
        sv[5] = __builtin_amdgcn_cvt_pk_f32_fp8((int)sq.z, true);
        sv[6] = __builtin_amdgcn_cvt_pk_f32_fp8((int)sq.w, false);
        sv[7] = __builtin_amdgcn_cvt_pk_f32_fp8((int)sq.w, true);
        st8p(wf_raw, 768, nloc, 2 * d0,       sv);
        st8p(wf_raw, 768, nloc, 2 * (d0 + 8), sv + 4);
      }
      PROC4(0, vA, g0)
      ISSUE4(vC, g0)
      __builtin_amdgcn_sched_barrier(0);
      PROC4(1, vB, g1)
      ISSUE4(vD, g1)
      __builtin_amdgcn_sched_barrier(0);
      PROC4(2, vC, g0)
      __builtin_amdgcn_sched_barrier(0);
      PROC4(3, vD, g1)

      st8p(wf_raw, 768, nloc, 2 * (ND + d0),         aR2);
      st8p(wf_raw, 768, nloc, 2 * (ND + d0 + 8),     aR2 + 4);
      st8p(wf_raw, 768, nloc, 2 * (2 * ND + d0),     aL2);
      st8p(wf_raw, 768, nloc, 2 * (2 * ND + d0 + 8), aL2 + 4);
    } else {
      // f32 fallback (ws too small): R10 structure
      const float* sp = nodeEmb + (rowbase + gn) * ND + d0;
      float sv[16];
      #pragma unroll
      for (int j = 0; j < 4; ++j){
        float4 s = *(const float4*)(sp + j * 4);
        sv[j*4+0]=s.x; sv[j*4+1]=s.y; sv[j*4+2]=s.z; sv[j*4+3]=s.w;
      }
      st8(wf_raw, 768, nloc, 2 * d0, sv);
      st8(wf_raw, 768, nloc, 2 * (d0 + 8), sv + 8);
      float aR[16], aL[16];
      #pragma unroll
      for (int i = 0; i < 16; ++i){ aR[i] = 0.0f; aL[i] = 0.0f; }
      const int4 vs[4] = {vA, vB, vC, vD};
      #pragma unroll
      for (int c4 = 0; c4 < 4; ++c4){
        int cidx[4] = {vs[c4].x, vs[c4].y, vs[c4].z, vs[c4].w};
        #pragma unroll
        for (int jj = 0; jj < 4; ++jj){
          const int c = c4 * 4 + jj;
          const int idx = cidx[jj];
          const float mk  = (idx > 0) ? 1.0f : 0.0f;
          const float wrc = one_sib ? (0.5f * mk) : (mk * (float)c * rdiv);
          const float wlc = (1.0f - wrc) * mk;
          const float* cp = nodeEmb + (rowbase + idx) * ND + d0;
          #pragma unroll
          for (int j = 0; j < 4; ++j){
            float4 u = *(const float4*)(cp + j * 4);
            aR[j*4+0] += wrc * u.x; aL[j*4+0] += wlc * u.x;
            aR[j*4+1] += wrc * u.y; aL[j*4+1] += wlc * u.y;
            aR[j*4+2] += wrc * u.z; aL[j*4+2] += wlc * u.z;
            aR[j*4+3] += wrc * u.w; aL[j*4+3] += wlc * u.w;
          }
        }
      }
      st8(wf_raw, 768, nloc, 2 * (ND + d0),         aR);
      st8(wf_raw, 768, nloc, 2 * (ND + d0 + 8),     aR + 8);
      st8(wf_raw, 768, nloc, 2 * (2 * ND + d0),     aL);
      st8(wf_raw, 768, nloc, 2 * (2 * ND + d0 + 8), aL + 8);
    }
  }
  __syncthreads();

  // ---- MFMA: 64 rows x 32 cols per wave, K=384; B frags amortized 2x ----
  {
    f32x4 acc[4][2];
    #pragma unroll
    for (int rf = 0; rf < 4; ++rf){
      acc[rf][0] = (f32x4){0.f, 0.f, 0.f, 0.f};
      acc[rf][1] = (f32x4){0.f, 0.f, 0.f, 0.f};
    }
    #pragma unroll 4
    for (int ks = 0; ks < 12; ++ks){
      bf16x8 B0 = __builtin_bit_cast(bf16x8, w1frag[((w * 2 + 0) * 12 + ks) * 64 + lane]);
      bf16x8 B1 = __builtin_bit_cast(bf16x8, w1frag[((w * 2 + 1) * 12 + ks) * 64 + lane]);
      const int koff = ks * 64 + ((lane >> 4) << 4);
      #pragma unroll
      for (int rf = 0; rf < 4; ++rf){
        const int row = rf * 16 + (lane & 15);
        bf16x8 a = __builtin_bit_cast(bf16x8, ldq(wf_raw, 768, row, koff));
        acc[rf][0] = __builtin_amdgcn_mfma_f32_16x16x32_bf16(a, B0, acc[rf][0], 0, 0, 0);
        acc[rf][1] = __builtin_amdgcn_mfma_f32_16x16x32_bf16(a, B1, acc[rf][1], 0, 0, 0);
      }
    }

    float m0 = -3.0e38f, m1 = -3.0e38f;
    #pragma unroll
    for (int rf = 0; rf < 4; ++rf)
      #pragma unroll
      for (int i = 0; i < 4; ++i){
        m0 = fmaxf(m0, acc[rf][0][i]);
        m1 = fmaxf(m1, acc[rf][1][i]);
      }
    m0 = fmaxf(m0, __shfl_xor(m0, 16, 64));
    m0 = fmaxf(m0, __shfl_xor(m0, 32, 64));
    m1 = fmaxf(m1, __shfl_xor(m1, 16, 64));
    m1 = fmaxf(m1, __shfl_xor(m1, 32, 64));
    if (lane < 16){
      atomicMax(pooled + b * NH + w * 32 + lane,      enc_f32(m0));
      atomicMax(pooled + b * NH + w * 32 + 16 + lane, enc_f32(m1));
    }
  }
}

// ---- final: h=tanh(pooled+b1) -> MFMA h@W2 -> tanh -> cosine(v1,v2) ----
__global__ __launch_bounds__(256) void tbcnn_final(
    const unsigned* __restrict__ pooled, const float* __restrict__ b1,
    const uint4* __restrict__ w2frag, const float* __restrict__ b2,
    float* __restrict__ out)
{
  __shared__ __align__(16) unsigned char hls[NB * 256];   // 32 x 128 bf16, swizzled
  __shared__ float os[NB * NH];
  const int t = threadIdx.x;
  const int lane = t & 63;
  const int w = t >> 6;

  {
    const int row = t >> 3;          // batch
    const int q = t & 7;
    const int d0 = q * 16;
    const unsigned* pp = pooled + row * NH + d0;
    const float* bp = b1 + d0;
    float hv[16];
    #pragma unroll
    for (int j = 0; j < 16; ++j) hv[j] = tanhf(dec_f32(pp[j]) + bp[j]);
    st8(hls, 256, row, 2 * d0, hv);
    st8(hls, 256, row, 2 * (d0 + 8), hv + 8);
  }
  __syncthreads();
  {
    f32x4 acc[2][2];
    #pragma unroll
    for (int rf = 0; rf < 2; ++rf){
      acc[rf][0] = (f32x4){0.f,0.f,0.f,0.f};
      acc[rf][1] = (f32x4){0.f,0.f,0.f,0.f};
    }
    #pragma unroll
    for (int ks = 0; ks < 4; ++ks){
      bf16x8 B0 = __builtin_bit_cast(bf16x8, w2frag[((w * 2 + 0) * 4 + ks) * 64 + lane]);
      bf16x8 B1 = __builtin_bit_cast(bf16x8, w2frag[((w * 2 + 1) * 4 + ks) * 64 + lane]);
      const int koff = ks * 64 + ((lane >> 4) << 4);
      #pragma unroll
      for (int rf = 0; rf < 2; ++rf){
        bf16x8 a = __builtin_bit_cast(bf16x8, ldq(hls, 256, rf * 16 + (lane & 15), koff));
        acc[rf][0] = __builtin_amdgcn_mfma_f32_16x16x32_bf16(a, B0, acc[rf][0], 0, 0, 0);
        acc[rf][1] = __builtin_amdgcn_mfma_f32_16x16x32_bf16(a, B1, acc[rf][1], 0, 0, 0);
      }
    }
    #pragma unroll
    for (int rf = 0; rf < 2; ++rf)
      #pragma unroll
      for (int cf = 0; cf < 2; ++cf){
        const int col = w * 32 + cf * 16 + (lane & 15);
        const float bias = b2[col];
        #pragma unroll
        for (int i = 0; i < 4; ++i){
          const int r = rf * 16 + (lane >> 4) * 4 + i;
          os[r * NH + col] = tanhf(acc[rf][cf][i] + bias);
        }
      }
  }
  __syncthreads();
  if (t < 16){
    float s12 = 0.f, s11 = 0.f, s22 = 0.f;
    #pragma unroll 4
    for (int d = 0; d < NH; ++d){
      float a = os[t * NH + d];
      float c = os[(t + 16) * NH + d];
      s12 += a * c; s11 += a * a; s22 += c * c;
    }
    float n1 = fmaxf(sqrtf(s11), 1e-8f);
    float n2 = fmaxf(sqrtf(s22), 1e-8f);
    out[t] = s12 / (n1 * n2);
  }
}

extern "C" void kernel_launch(void* const* d_in, const int* in_sizes, int n_in,
                              void* d_out, int out_size, void* d_ws, size_t ws_size,
                              hipStream_t stream)
{
  const int*   children = (const int*)d_in[0];
  const float* nodeEmb  = (const float*)d_in[1];
  const float* W1       = (const float*)d_in[2];
  const float* b1       = (const float*)d_in[3];
  const float* W2       = (const float*)d_in[4];
  const float* b2       = (const float*)d_in[5];
  float* out = (float*)d_out;

  unsigned* pooled      = (unsigned*)((char*)d_ws + OFF_POOLED);
  uint4* w1frag         = (uint4*)((char*)d_ws + OFF_W1);
  uint4* w2frag         = (uint4*)((char*)d_ws + OFF_W2);
  unsigned char* embF8  = (unsigned char*)((char*)d_ws + OFF_EMB);

  const bool f8 = (ws_size >= WS_NEED_F8);

  tbcnn_prep<<<2080, 256, 0, stream>>>(nodeEmb, W1, W2, pooled, w1frag, w2frag, embF8, f8 ? 1 : 0);
  if (f8)
    tbcnn_main<true><<<NBLK, 256, 0, stream>>>(children, nodeEmb, embF8, w1frag, pooled);
  else
    tbcnn_main<false><<<NBLK, 256, 0, stream>>>(children, nodeEmb, embF8, w1frag, pooled);
  tbcnn_final<<<1, 256, 0, stream>>>(pooled, b1, w2frag, b2, out);
}